// Round 8
// baseline (512.061 us; speedup 1.0000x reference)
//
#include <hip/hip_runtime.h>
#include <hip/hip_fp16.h>
#include <stdint.h>

#define G      128
#define OUTW   128
#define RNUM   6

typedef unsigned short us;
typedef _Float16 f16x8 __attribute__((ext_vector_type(8)));
typedef float    f32x4 __attribute__((ext_vector_type(4)));

__device__ inline float h2f(us u) { __half h; *(us*)&h = u; return __half2float(h); }
__device__ inline us f2h(float f) { __half h = __float2half(f); return *(us*)&h; }
__device__ inline float2 h22(int u) { return __half22float2(*(__half2*)&u); }

union FragU { f16x8 v; ushort4 u[2]; };

// ---------------- scan: 3-phase over n = N*RNUM segments ----------------
__global__ __launch_bounds__(256)
void scan_part(const int* __restrict__ cnt, int* __restrict__ bsum, int n) {
    __shared__ int s[256];
    int base = blockIdx.x * 1024, t = threadIdx.x;
    int v = 0;
    for (int j = 0; j < 4; ++j) { int idx = base + j * 256 + t; if (idx < n) v += cnt[idx]; }
    s[t] = v; __syncthreads();
    for (int off = 128; off; off >>= 1) { if (t < off) s[t] += s[t + off]; __syncthreads(); }
    if (!t) bsum[blockIdx.x] = s[0];
}

__global__ __launch_bounds__(512)
void scan_top(const int* __restrict__ bsum, int* __restrict__ boff,
              int* __restrict__ segptr, int nb, int n) {
    __shared__ int s[512];
    int t = threadIdx.x;
    int v = (t < nb) ? bsum[t] : 0;
    s[t] = v;
    __syncthreads();
    for (int off = 1; off < 512; off <<= 1) {
        int y = (t >= off) ? s[t - off] : 0;
        __syncthreads();
        s[t] += y;
        __syncthreads();
    }
    if (t < nb) boff[t + 1] = s[t];
    if (!t) boff[0] = 0;
    if (t == nb - 1) segptr[n] = s[t];     // grand total = E
}

__global__ __launch_bounds__(256)
void scan_apply(const int* __restrict__ cnt, const int* __restrict__ boff,
                int* __restrict__ segptr, int* __restrict__ cursor, int n) {
    __shared__ int L[1024];
    __shared__ int SS[256];
    int base = blockIdx.x * 1024, t = threadIdx.x;
    for (int j = 0; j < 4; ++j) { int idx = base + j * 256 + t; L[j * 256 + t] = (idx < n) ? cnt[idx] : 0; }
    __syncthreads();
    int s0 = L[t*4] + L[t*4+1] + L[t*4+2] + L[t*4+3];
    SS[t] = s0; __syncthreads();
    for (int off = 1; off < 256; off <<= 1) {
        int y = (t >= off) ? SS[t - off] : 0;
        __syncthreads();
        SS[t] += y;
        __syncthreads();
    }
    int e0 = (t ? SS[t - 1] : 0) + boff[blockIdx.x];
    int4 ov;
    int a;
    a = L[t*4+0]; ov.x = e0; e0 += a;
    a = L[t*4+1]; ov.y = e0; e0 += a;
    a = L[t*4+2]; ov.z = e0; e0 += a;
    a = L[t*4+3]; ov.w = e0; e0 += a;
    int idx0 = base + t * 4;
    if (idx0 + 3 < n) {
        *(int4*)(segptr + idx0) = ov;
        *(int4*)(cursor + idx0) = ov;
    } else {
        int vals[4] = {ov.x, ov.y, ov.z, ov.w};
        for (int k = 0; k < 4; ++k)
            if (idx0 + k < n) { segptr[idx0 + k] = vals[k]; cursor[idx0 + k] = vals[k]; }
    }
}

// ---------------- K3: scatter edges into composite CSR ----------------
__global__ void scatter_kernel(const int* __restrict__ ei, const int* __restrict__ et,
                               int* __restrict__ cursor, unsigned* __restrict__ esrc,
                               int N, int E) {
    int e = blockIdx.x * blockDim.x + threadIdx.x;
    if (e >= E) return;
    int src = ei[e];
    int dst = ei[E + e];
    int r   = et[e];
    int pos = atomicAdd(&cursor[dst * RNUM + r], 1);
    esrc[pos] = (unsigned)src;
}

// ---------------- prep2: count + xhalf + wconv_rgcn + wconv_qkvs fused ----------------
__global__ __launch_bounds__(256)
void prep2_kernel(const int* __restrict__ ei, const int* __restrict__ et,
                  int* __restrict__ segcnt, int E, int eb,
                  const float* __restrict__ x, us* __restrict__ xh,
                  const float* __restrict__ Wrel, const float* __restrict__ Wroot,
                  ushort4* __restrict__ Btr,
                  const float* __restrict__ Wq, const float* __restrict__ Wk,
                  const float* __restrict__ Wv, const float* __restrict__ Ws,
                  ushort4* __restrict__ Btq, int xblocks) {
    int b = blockIdx.x;
    if (b < eb) {
        int e = b * 256 + threadIdx.x;
        if (e < E) {
            int dst = ei[E + e];
            int r   = et[e];
            atomicAdd(&segcnt[dst * RNUM + r], 1);
        }
    } else if (b < eb + xblocks) {
        int i = (b - eb) * 256 + threadIdx.x;      // i < N*G/8 exactly
        float4 a = ((const float4*)x)[2*i];
        float4 c = ((const float4*)x)[2*i+1];
        ushort4 u0 = { f2h(a.x), f2h(a.y), f2h(a.z), f2h(a.w) };
        ushort4 u1 = { f2h(c.x), f2h(c.y), f2h(c.z), f2h(c.w) };
        ((ushort4*)xh)[2*i]   = u0;
        ((ushort4*)xh)[2*i+1] = u1;
    } else if (b < eb + xblocks + 112) {
        int idx = (b - eb - xblocks) * 256 + threadIdx.x;   // < 224*128 exactly
        int kq = idx >> 7, n = idx & 127;
        ushort4 o;
        us* op = (us*)&o;
#pragma unroll
        for (int i = 0; i < 4; ++i) {
            int k = 4 * kq + i;
            float v = (k < 768) ? Wrel[(size_t)k * 128 + n] : Wroot[(size_t)(k - 768) * 128 + n];
            op[i] = f2h(v);
        }
        Btr[idx] = o;
    } else {
        int idx = (b - eb - xblocks - 112) * 256 + threadIdx.x;  // < 32*512 exactly
        int kq = idx >> 9, n = idx & 511;
        int quad = n >> 7, nl = n & 127;
        const float* W = (quad == 0) ? Wq : (quad == 1) ? Wk : (quad == 2) ? Wv : Ws;
        ushort4 o;
        us* op = (us*)&o;
#pragma unroll
        for (int i = 0; i < 4; ++i) {
            int k = 4 * kq + i;
            op[i] = f2h(W[(size_t)k * 128 + nl]);
        }
        Btq[idx] = o;
    }
}

// ---------------- K4: aggregation (wave/node, 8-deep gathers, scalar rel-flush) ----------------
__global__ __launch_bounds__(256)
void agg_kernel(const us* __restrict__ xh, const int* __restrict__ segptr,
                const unsigned* __restrict__ esrc, us* __restrict__ meanh, int N) {
    const int wv = threadIdx.x >> 6, l = threadIdx.x & 63;
    const int i = blockIdx.x * 4 + wv;
    if (i >= N) return;
    const int e0 = __builtin_amdgcn_readfirstlane(segptr[i * RNUM]);
    const int e1 = __builtin_amdgcn_readfirstlane(segptr[i * RNUM + RNUM]);

    int rcur = 0;
    int sstart = e0;
    int bnext = __builtin_amdgcn_readfirstlane(segptr[i * RNUM + 1]);
    float2 a = {0.f, 0.f};
    us* wbase = meanh + (size_t)i * 768 + 2 * l;

#define FLUSH() { \
    float sc_ = 1.f / fmaxf((float)(bnext - sstart), 1.f); \
    ushort2 t2_ = { f2h(a.x * sc_), f2h(a.y * sc_) }; \
    *(ushort2*)(wbase + rcur * 128) = t2_; \
    a.x = 0.f; a.y = 0.f; \
    sstart = bnext; ++rcur; \
    if (rcur < RNUM) bnext = __builtin_amdgcn_readfirstlane(segptr[i * RNUM + rcur + 1]); }

#define GET(J) ((unsigned)__shfl((int)pv, (J)))
#define LX(Q)  (*(const ushort2*)(xh + (size_t)(Q) * G + 2 * l))
#define STEP(U) { while (p >= bnext && rcur < RNUM - 1) FLUSH(); \
                  a.x += h2f((U).x); a.y += h2f((U).y); ++p; }

    int p = e0;
    for (int wb = e0; wb < e1; wb += 64) {
        const int nc = min(64, e1 - wb);
        unsigned pv = (wb + l < e1) ? esrc[wb + l] : 0u;
        int j = 0;
        while (j + 8 <= nc) {
            unsigned q0 = GET(j+0), q1 = GET(j+1), q2 = GET(j+2), q3 = GET(j+3);
            unsigned q4 = GET(j+4), q5 = GET(j+5), q6 = GET(j+6), q7 = GET(j+7);
            ushort2 u0 = LX(q0), u1 = LX(q1), u2 = LX(q2), u3 = LX(q3);
            ushort2 u4 = LX(q4), u5 = LX(q5), u6 = LX(q6), u7 = LX(q7);
            STEP(u0); STEP(u1); STEP(u2); STEP(u3);
            STEP(u4); STEP(u5); STEP(u6); STEP(u7);
            j += 8;
        }
        while (j + 2 <= nc) {
            unsigned q0 = GET(j), q1 = GET(j+1);
            ushort2 u0 = LX(q0), u1 = LX(q1);
            STEP(u0); STEP(u1);
            j += 2;
        }
        if (j < nc) {
            unsigned q0 = GET(j);
            ushort2 u0 = LX(q0);
            STEP(u0);
            ++j;
        }
    }
    while (rcur < RNUM) FLUSH();
#undef STEP
#undef LX
#undef GET
#undef FLUSH
}

// ---------------- K5: FUSED rgcn GEMM + qkvs GEMM (LDS handoff, no xrh) ----------------
// 256 thr / 4 waves; 128-row tile. Phase1: rgcn -> LDS X[128][136] fp16 (pad 8 us).
// Phase2: wave w = quadrant w of q|k|v|skip over all 128 rows.
__global__ __launch_bounds__(256)
void rgcn_qkvs(const us* __restrict__ xh, const us* __restrict__ meanh,
               const ushort4* __restrict__ Btr, const float* __restrict__ brg,
               const ushort4* __restrict__ Btq,
               const float* __restrict__ bq, const float* __restrict__ bk,
               const float* __restrict__ bv, const float* __restrict__ bs,
               us* __restrict__ qsh, us* __restrict__ kvh, int N) {
    __shared__ us X[128][136];
    const int tid = threadIdx.x;
    const int w = tid >> 6, l = tid & 63;
    const int lh = l >> 4, lm = l & 15;
    const int blockbase = blockIdx.x * 128;
    const int rowbase = blockbase + w * 32;

    // ---------- phase 1: RGCN ----------
    {
        const us* am[2];
        const us* ar[2];
#pragma unroll
        for (int tt = 0; tt < 2; ++tt) {
            int gr = min(rowbase + tt * 16 + lm, N - 1);
            am[tt] = meanh + (size_t)gr * 768;
            ar[tt] = xh + (size_t)gr * 128;
        }

        f32x4 acc[2][8];
#pragma unroll
        for (int tt = 0; tt < 2; ++tt)
#pragma unroll
            for (int ct = 0; ct < 8; ++ct) {
                float b = brg[ct * 16 + lm];
                acc[tt][ct] = (f32x4){b, b, b, b};
            }

        for (int s = 0; s < 24; ++s) {
            const int kqg = s * 8 + lh;
            const ushort4* B0 = Btr + (size_t)kqg * 128 + lm;
            const ushort4* B1 = B0 + 4 * 128;
            FragU bf[8];
#pragma unroll
            for (int ct = 0; ct < 8; ++ct) { bf[ct].u[0] = B0[ct * 16]; bf[ct].u[1] = B1[ct * 16]; }
#pragma unroll
            for (int tt = 0; tt < 2; ++tt) {
                FragU af;
                af.u[0] = *(const ushort4*)(am[tt] + s * 32 + 4 * lh);
                af.u[1] = *(const ushort4*)(am[tt] + s * 32 + 4 * lh + 16);
#pragma unroll
                for (int ct = 0; ct < 8; ++ct)
                    acc[tt][ct] = __builtin_amdgcn_mfma_f32_16x16x32_f16(af.v, bf[ct].v, acc[tt][ct], 0, 0, 0);
            }
        }
#pragma unroll
        for (int s = 0; s < 4; ++s) {
            const int kqg = 192 + s * 8 + lh;
            const ushort4* B0 = Btr + (size_t)kqg * 128 + lm;
            const ushort4* B1 = B0 + 4 * 128;
            FragU bf[8];
#pragma unroll
            for (int ct = 0; ct < 8; ++ct) { bf[ct].u[0] = B0[ct * 16]; bf[ct].u[1] = B1[ct * 16]; }
#pragma unroll
            for (int tt = 0; tt < 2; ++tt) {
                FragU af;
                af.u[0] = *(const ushort4*)(ar[tt] + s * 32 + 4 * lh);
                af.u[1] = *(const ushort4*)(ar[tt] + s * 32 + 4 * lh + 16);
#pragma unroll
                for (int ct = 0; ct < 8; ++ct)
                    acc[tt][ct] = __builtin_amdgcn_mfma_f32_16x16x32_f16(af.v, bf[ct].v, acc[tt][ct], 0, 0, 0);
            }
        }

        // D-frag -> LDS (same f16 rounding as old xrh roundtrip)
#pragma unroll
        for (int tt = 0; tt < 2; ++tt)
#pragma unroll
            for (int ct = 0; ct < 8; ++ct)
#pragma unroll
                for (int i = 0; i < 4; ++i)
                    X[w * 32 + tt * 16 + 4 * lh + i][ct * 16 + lm] = f2h(acc[tt][ct][i]);
    }
    __syncthreads();

    // ---------- phase 2: q|k|v|skip ; wave w = quadrant w ----------
    const int quad = w;
    const float* bias = (quad == 0) ? bq : (quad == 1) ? bk : (quad == 2) ? bv : bs;

    for (int tp = 0; tp < 4; ++tp) {
        f32x4 a2[2][8];
#pragma unroll
        for (int tt = 0; tt < 2; ++tt)
#pragma unroll
            for (int ct = 0; ct < 8; ++ct) {
                float b = bias[ct * 16 + lm];
                a2[tt][ct] = (f32x4){b, b, b, b};
            }
#pragma unroll
        for (int s = 0; s < 4; ++s) {
            const int kq = s * 8 + lh;
            const ushort4* B0 = Btq + (size_t)kq * 512 + quad * 128 + lm;
            const ushort4* B1 = B0 + 4 * 512;
            FragU bf[8];
#pragma unroll
            for (int ct = 0; ct < 8; ++ct) { bf[ct].u[0] = B0[ct * 16]; bf[ct].u[1] = B1[ct * 16]; }
#pragma unroll
            for (int tt = 0; tt < 2; ++tt) {
                const int row = tp * 32 + tt * 16 + lm;
                FragU af;
                af.u[0] = *(const ushort4*)(&X[row][4 * kq]);
                af.u[1] = *(const ushort4*)(&X[row][4 * kq + 16]);
#pragma unroll
                for (int ct = 0; ct < 8; ++ct)
                    a2[tt][ct] = __builtin_amdgcn_mfma_f32_16x16x32_f16(af.v, bf[ct].v, a2[tt][ct], 0, 0, 0);
            }
        }
        if (quad == 0 || quad == 3) {
            const int off = (quad == 0) ? 0 : 128;
#pragma unroll
            for (int tt = 0; tt < 2; ++tt)
#pragma unroll
                for (int ct = 0; ct < 8; ++ct)
#pragma unroll
                    for (int i = 0; i < 4; ++i) {
                        int r = blockbase + tp * 32 + tt * 16 + 4 * lh + i;
                        if (r < N) qsh[(size_t)r * 256 + off + ct * 16 + lm] = f2h(a2[tt][ct][i]);
                    }
        } else {
            const int off = (quad == 1) ? 0 : 2;
#pragma unroll
            for (int tt = 0; tt < 2; ++tt)
#pragma unroll
                for (int ct = 0; ct < 8; ++ct)
#pragma unroll
                    for (int i = 0; i < 4; ++i) {
                        int r = blockbase + tp * 32 + tt * 16 + 4 * lh + i;
                        int col = ct * 16 + lm;
                        if (r < N) kvh[(size_t)r * 256 + (col >> 1) * 4 + (col & 1) + off] = f2h(a2[tt][ct][i]);
                    }
        }
    }
}

// ---------------- K7: attention — 32 lanes/node, 2 nodes/wave, 8-deep online softmax + BN ----------------
__global__ __launch_bounds__(256)
void attn_kernel(const us* __restrict__ qsh, const us* __restrict__ kvh,
                 const int* __restrict__ segptr, const unsigned* __restrict__ esrc,
                 float* __restrict__ out, float* __restrict__ bnS,
                 float* __restrict__ bnQ, int N) {
    __shared__ float sS[128], sQ[128];
    const int tid = threadIdx.x;
    if (tid < 128) { sS[tid] = 0.f; sQ[tid] = 0.f; }
    __syncthreads();

    const int wv = tid >> 6, l = tid & 63;
    const int hh = l >> 5, ll = l & 31;
    const int stride = gridDim.x * 8;
    const float QS = 0.17677669529663687f;   // 1/sqrt(32)
    float4 bsum = {0,0,0,0}, bsq = {0,0,0,0};

#define SCORE(D, S) { \
    float2 ka_ = h22((D).x), kb_ = h22((D).z); \
    float t_ = q4.x*ka_.x + q4.y*ka_.y + q4.z*kb_.x + q4.w*kb_.y; \
    t_ += __shfl_xor(t_, 1, 8); t_ += __shfl_xor(t_, 2, 8); t_ += __shfl_xor(t_, 4, 8); \
    S = t_; }

    for (int ibase = blockIdx.x * 8 + wv * 2; ibase < N; ibase += stride) {
        const bool act = (ibase + hh) < N;
        const int i = min(ibase + hh, N - 1);

        int2 qu = *(const int2*)(qsh + (size_t)i * 256 + 4 * ll);
        float2 qa = h22(qu.x), qb = h22(qu.y);
        float4 q4 = { qa.x * QS, qa.y * QS, qb.x * QS, qb.y * QS };

        float m = -INFINITY, den = 0.f;
        float4 acc = {0,0,0,0};
        const int e0 = segptr[(size_t)i * RNUM], e1 = segptr[(size_t)i * RNUM + RNUM];

        for (int wb = e0; wb < e1; wb += 32) {
            const int nc = min(32, e1 - wb);
            unsigned pv = (wb + ll < e1) ? esrc[wb + ll] : 0u;
            int j = 0;
            for (; j + 8 <= nc; j += 8) {
                unsigned p0 = (unsigned)__shfl((int)pv, j+0, 32);
                unsigned p1 = (unsigned)__shfl((int)pv, j+1, 32);
                unsigned p2 = (unsigned)__shfl((int)pv, j+2, 32);
                unsigned p3 = (unsigned)__shfl((int)pv, j+3, 32);
                unsigned p4 = (unsigned)__shfl((int)pv, j+4, 32);
                unsigned p5 = (unsigned)__shfl((int)pv, j+5, 32);
                unsigned p6 = (unsigned)__shfl((int)pv, j+6, 32);
                unsigned p7 = (unsigned)__shfl((int)pv, j+7, 32);
                int4 d0 = *(const int4*)(kvh + (size_t)p0 * 256 + 8 * ll);
                int4 d1 = *(const int4*)(kvh + (size_t)p1 * 256 + 8 * ll);
                int4 d2 = *(const int4*)(kvh + (size_t)p2 * 256 + 8 * ll);
                int4 d3 = *(const int4*)(kvh + (size_t)p3 * 256 + 8 * ll);
                int4 d4 = *(const int4*)(kvh + (size_t)p4 * 256 + 8 * ll);
                int4 d5 = *(const int4*)(kvh + (size_t)p5 * 256 + 8 * ll);
                int4 d6 = *(const int4*)(kvh + (size_t)p6 * 256 + 8 * ll);
                int4 d7 = *(const int4*)(kvh + (size_t)p7 * 256 + 8 * ll);
                float s0, s1, s2, s3, s4, s5, s6, s7;
                SCORE(d0, s0); SCORE(d1, s1); SCORE(d2, s2); SCORE(d3, s3);
                SCORE(d4, s4); SCORE(d5, s5); SCORE(d6, s6); SCORE(d7, s7);
                float mx = fmaxf(m, fmaxf(
                    fmaxf(fmaxf(s0, s1), fmaxf(s2, s3)),
                    fmaxf(fmaxf(s4, s5), fmaxf(s6, s7))));
                float rs = __expf(m - mx);
                float w0 = __expf(s0 - mx), w1 = __expf(s1 - mx);
                float w2 = __expf(s2 - mx), w3 = __expf(s3 - mx);
                float w4 = __expf(s4 - mx), w5 = __expf(s5 - mx);
                float w6 = __expf(s6 - mx), w7 = __expf(s7 - mx);
                den = den * rs + (((w0 + w1) + (w2 + w3)) + ((w4 + w5) + (w6 + w7)));
                float2 va0 = h22(d0.y), vb0 = h22(d0.w);
                float2 va1 = h22(d1.y), vb1 = h22(d1.w);
                float2 va2 = h22(d2.y), vb2 = h22(d2.w);
                float2 va3 = h22(d3.y), vb3 = h22(d3.w);
                float2 va4 = h22(d4.y), vb4 = h22(d4.w);
                float2 va5 = h22(d5.y), vb5 = h22(d5.w);
                float2 va6 = h22(d6.y), vb6 = h22(d6.w);
                float2 va7 = h22(d7.y), vb7 = h22(d7.w);
                acc.x = acc.x * rs + ((w0*va0.x + w1*va1.x) + (w2*va2.x + w3*va3.x))
                                   + ((w4*va4.x + w5*va5.x) + (w6*va6.x + w7*va7.x));
                acc.y = acc.y * rs + ((w0*va0.y + w1*va1.y) + (w2*va2.y + w3*va3.y))
                                   + ((w4*va4.y + w5*va5.y) + (w6*va6.y + w7*va7.y));
                acc.z = acc.z * rs + ((w0*vb0.x + w1*vb1.x) + (w2*vb2.x + w3*vb3.x))
                                   + ((w4*vb4.x + w5*vb5.x) + (w6*vb6.x + w7*vb7.x));
                acc.w = acc.w * rs + ((w0*vb0.y + w1*vb1.y) + (w2*vb2.y + w3*vb3.y))
                                   + ((w4*vb4.y + w5*vb5.y) + (w6*vb6.y + w7*vb7.y));
                m = mx;
            }
            for (; j + 4 <= nc; j += 4) {
                unsigned p0 = (unsigned)__shfl((int)pv, j+0, 32);
                unsigned p1 = (unsigned)__shfl((int)pv, j+1, 32);
                unsigned p2 = (unsigned)__shfl((int)pv, j+2, 32);
                unsigned p3 = (unsigned)__shfl((int)pv, j+3, 32);
                int4 d0 = *(const int4*)(kvh + (size_t)p0 * 256 + 8 * ll);
                int4 d1 = *(const int4*)(kvh + (size_t)p1 * 256 + 8 * ll);
                int4 d2 = *(const int4*)(kvh + (size_t)p2 * 256 + 8 * ll);
                int4 d3 = *(const int4*)(kvh + (size_t)p3 * 256 + 8 * ll);
                float s0, s1, s2, s3;
                SCORE(d0, s0); SCORE(d1, s1); SCORE(d2, s2); SCORE(d3, s3);
                float mx = fmaxf(m, fmaxf(fmaxf(s0, s1), fmaxf(s2, s3)));
                float rs = __expf(m - mx);
                float w0 = __expf(s0 - mx), w1 = __expf(s1 - mx);
                float w2 = __expf(s2 - mx), w3 = __expf(s3 - mx);
                den = den * rs + ((w0 + w1) + (w2 + w3));
                float2 va0 = h22(d0.y), vb0 = h22(d0.w);
                float2 va1 = h22(d1.y), vb1 = h22(d1.w);
                float2 va2 = h22(d2.y), vb2 = h22(d2.w);
                float2 va3 = h22(d3.y), vb3 = h22(d3.w);
                acc.x = acc.x * rs + w0*va0.x + w1*va1.x + w2*va2.x + w3*va3.x;
                acc.y = acc.y * rs + w0*va0.y + w1*va1.y + w2*va2.y + w3*va3.y;
                acc.z = acc.z * rs + w0*vb0.x + w1*vb1.x + w2*vb2.x + w3*vb3.x;
                acc.w = acc.w * rs + w0*vb0.y + w1*vb1.y + w2*vb2.y + w3*vb3.y;
                m = mx;
            }
            for (; j < nc; ++j) {
                unsigned p0 = (unsigned)__shfl((int)pv, j, 32);
                int4 d0 = *(const int4*)(kvh + (size_t)p0 * 256 + 8 * ll);
                float s0; SCORE(d0, s0);
                float mx = fmaxf(m, s0);
                float rs = __expf(m - mx);
                float w0 = __expf(s0 - mx);
                den = den * rs + w0;
                float2 va0 = h22(d0.y), vb0 = h22(d0.w);
                acc.x = acc.x * rs + w0 * va0.x;
                acc.y = acc.y * rs + w0 * va0.y;
                acc.z = acc.z * rs + w0 * vb0.x;
                acc.w = acc.w * rs + w0 * vb0.y;
                m = mx;
            }
        }

        float inv = 1.f / (den + 1e-16f);
        int2 su = *(const int2*)(qsh + (size_t)i * 256 + 128 + 4 * ll);
        float2 sa = h22(su.x), sb = h22(su.y);
        float4 o = { acc.x * inv + sa.x, acc.y * inv + sa.y,
                     acc.z * inv + sb.x, acc.w * inv + sb.y };
        if (act) {
            *(float4*)(out + (size_t)i * OUTW + 4 * ll) = o;
            bsum.x += o.x; bsum.y += o.y; bsum.z += o.z; bsum.w += o.w;
            bsq.x += o.x*o.x; bsq.y += o.y*o.y; bsq.z += o.z*o.z; bsq.w += o.w*o.w;
        }
    }
#undef SCORE

    atomicAdd(&sS[4*ll + 0], bsum.x);
    atomicAdd(&sS[4*ll + 1], bsum.y);
    atomicAdd(&sS[4*ll + 2], bsum.z);
    atomicAdd(&sS[4*ll + 3], bsum.w);
    atomicAdd(&sQ[4*ll + 0], bsq.x);
    atomicAdd(&sQ[4*ll + 1], bsq.y);
    atomicAdd(&sQ[4*ll + 2], bsq.z);
    atomicAdd(&sQ[4*ll + 3], bsq.w);
    __syncthreads();
    if (tid < 128) {
        atomicAdd(&bnS[tid], sS[tid]);
        atomicAdd(&bnQ[tid], sQ[tid]);
    }
}

// ---------------- K8: BN stats (inline) + apply + LeakyReLU ----------------
__global__ __launch_bounds__(256)
void apply_kernel(float* __restrict__ out, const float* __restrict__ bnS,
                  const float* __restrict__ bnQ, const float* __restrict__ gamma,
                  const float* __restrict__ beta, int N, int total4) {
    __shared__ float A_s[128], B_s[128];
    const int tid = threadIdx.x;
    if (tid < 128) {
        float fN  = (float)N;
        float mu  = bnS[tid] / fN;
        float var = bnQ[tid] / fN - mu * mu;
        float rv  = rsqrtf(var + 1e-5f);
        float A   = rv * gamma[tid];
        A_s[tid] = A;
        B_s[tid] = beta[tid] - mu * A;
    }
    __syncthreads();
    for (int idx4 = blockIdx.x * 256 + tid; idx4 < total4; idx4 += gridDim.x * 256) {
        float4 v = ((const float4*)out)[idx4];
        int c0 = (idx4 * 4) & 127;
        float y;
        y = A_s[c0    ] * v.x + B_s[c0    ]; v.x = (y > 0.f) ? y : 0.01f * y;
        y = A_s[c0 + 1] * v.y + B_s[c0 + 1]; v.y = (y > 0.f) ? y : 0.01f * y;
        y = A_s[c0 + 2] * v.z + B_s[c0 + 2]; v.z = (y > 0.f) ? y : 0.01f * y;
        y = A_s[c0 + 3] * v.w + B_s[c0 + 3]; v.w = (y > 0.f) ? y : 0.01f * y;
        ((float4*)out)[idx4] = v;
    }
}

// ---------------- launch ----------------
static inline char* alignp(char* p) {
    return (char*)(((uintptr_t)p + 255) & ~(uintptr_t)255);
}

extern "C" void kernel_launch(void* const* d_in, const int* in_sizes, int n_in,
                              void* d_out, int out_size, void* d_ws, size_t ws_size,
                              hipStream_t stream) {
    const float* x     = (const float*)d_in[0];
    const int*   ei    = (const int*)  d_in[2];
    const int*   et    = (const int*)  d_in[3];
    const float* Wrel  = (const float*)d_in[4];
    const float* Wroot = (const float*)d_in[5];
    const float* brg   = (const float*)d_in[6];
    const float* Wq    = (const float*)d_in[7];
    const float* bq    = (const float*)d_in[8];
    const float* Wk    = (const float*)d_in[9];
    const float* bk    = (const float*)d_in[10];
    const float* Wv    = (const float*)d_in[11];
    const float* bv    = (const float*)d_in[12];
    const float* Wsk   = (const float*)d_in[13];
    const float* bsk   = (const float*)d_in[14];
    const float* gamma = (const float*)d_in[15];
    const float* beta  = (const float*)d_in[16];
    float* out = (float*)d_out;

    const int N = in_sizes[0] / G;
    const int E = in_sizes[3];
    const int NSEG = N * RNUM;
    const int NB_SCAN = (NSEG + 1023) / 1024;   // <= 512

    // ---- workspace carve ----
    char* w = (char*)d_ws;
    int* segcnt = (int*)w;           w += (size_t)NSEG * 4;
    float* bnS = (float*)w;          w += 128 * 4;
    float* bnQ = (float*)w;          w += 128 * 4;
    size_t zero_bytes = (size_t)(w - (char*)d_ws);
    w = alignp(w);
    int* bsum  = (int*)w;            w += 512 * 4;
    int* boff  = (int*)w;            w += 513 * 4;
    w = alignp(w);
    int* segptr = (int*)w;           w += (size_t)(NSEG + 1) * 4;
    w = alignp(w);
    int* cursor = (int*)w;           w += (size_t)NSEG * 4;
    w = alignp(w);
    unsigned* esrc = (unsigned*)w;   w += (size_t)E * 4;
    w = alignp(w);
    us* xh     = (us*)w;             w += (size_t)N * G * 2;
    w = alignp(w);
    ushort4* Btr = (ushort4*)w;      w += (size_t)224 * 128 * 8;
    w = alignp(w);
    ushort4* Btq = (ushort4*)w;      w += (size_t)32 * 512 * 8;
    w = alignp(w);
    // aliased region: meanh [N][768] fp16 row-major (76.8MB);
    // later qsh [N][256] fp16 (25.6MB) + kvh [N][256] fp16 (25.6MB)
    us* meanh = (us*)w;
    us* qsh   = (us*)w;
    us* kvh   = (us*)(w + (size_t)N * 256 * 2);

    hipMemsetAsync(d_ws, 0, zero_bytes, stream);

    int eb = (E + 255) / 256;
    int xblocks = N * G / 8 / 256;               // 3125
    prep2_kernel<<<eb + xblocks + 112 + 64, 256, 0, stream>>>(
        ei, et, segcnt, E, eb, x, xh, Wrel, Wroot, Btr, Wq, Wk, Wv, Wsk, Btq, xblocks);

    scan_part<<<NB_SCAN, 256, 0, stream>>>(segcnt, bsum, NSEG);
    scan_top<<<1, 512, 0, stream>>>(bsum, boff, segptr, NB_SCAN, NSEG);
    scan_apply<<<NB_SCAN, 256, 0, stream>>>(segcnt, boff, segptr, cursor, NSEG);

    scatter_kernel<<<eb, 256, 0, stream>>>(ei, et, cursor, esrc, N, E);

    agg_kernel<<<(N + 3) / 4, 256, 0, stream>>>(xh, segptr, esrc, meanh, N);

    rgcn_qkvs<<<(N + 127) / 128, 256, 0, stream>>>(xh, meanh, Btr, brg, Btq,
                                                   bq, bk, bv, bsk, qsh, kvh, N);

    attn_kernel<<<(N + 7) / 8, 256, 0, stream>>>(qsh, kvh, segptr, esrc, out, bnS, bnQ, N);

    int total4 = N * OUTW / 4;
    apply_kernel<<<2048, 256, 0, stream>>>(out, bnS, bnQ, gamma, beta, N, total4);
}

// Round 9
// 427.222 us; speedup vs baseline: 1.1986x; 1.1986x over previous
//
#include <hip/hip_runtime.h>
#include <hip/hip_fp16.h>
#include <stdint.h>

#define G      128
#define OUTW   128
#define RNUM   6

typedef unsigned short us;
typedef _Float16 f16x8 __attribute__((ext_vector_type(8)));
typedef float    f32x4 __attribute__((ext_vector_type(4)));

__device__ inline float h2f(us u) { __half h; *(us*)&h = u; return __half2float(h); }
__device__ inline us f2h(float f) { __half h = __float2half(f); return *(us*)&h; }
__device__ inline float2 h22(int u) { return __half22float2(*(__half2*)&u); }

union FragU { f16x8 v; ushort4 u[2]; };

// ---------------- scan: 3-phase over n = N*RNUM segments ----------------
__global__ __launch_bounds__(256)
void scan_part(const int* __restrict__ cnt, int* __restrict__ bsum, int n) {
    __shared__ int s[256];
    int base = blockIdx.x * 1024, t = threadIdx.x;
    int v = 0;
    for (int j = 0; j < 4; ++j) { int idx = base + j * 256 + t; if (idx < n) v += cnt[idx]; }
    s[t] = v; __syncthreads();
    for (int off = 128; off; off >>= 1) { if (t < off) s[t] += s[t + off]; __syncthreads(); }
    if (!t) bsum[blockIdx.x] = s[0];
}

__global__ __launch_bounds__(512)
void scan_top(const int* __restrict__ bsum, int* __restrict__ boff,
              int* __restrict__ segptr, int nb, int n) {
    __shared__ int s[512];
    int t = threadIdx.x;
    int v = (t < nb) ? bsum[t] : 0;
    s[t] = v;
    __syncthreads();
    for (int off = 1; off < 512; off <<= 1) {
        int y = (t >= off) ? s[t - off] : 0;
        __syncthreads();
        s[t] += y;
        __syncthreads();
    }
    if (t < nb) boff[t + 1] = s[t];
    if (!t) boff[0] = 0;
    if (t == nb - 1) segptr[n] = s[t];     // grand total = E
}

__global__ __launch_bounds__(256)
void scan_apply(const int* __restrict__ cnt, const int* __restrict__ boff,
                int* __restrict__ segptr, int* __restrict__ cursor, int n) {
    __shared__ int L[1024];
    __shared__ int SS[256];
    int base = blockIdx.x * 1024, t = threadIdx.x;
    for (int j = 0; j < 4; ++j) { int idx = base + j * 256 + t; L[j * 256 + t] = (idx < n) ? cnt[idx] : 0; }
    __syncthreads();
    int s0 = L[t*4] + L[t*4+1] + L[t*4+2] + L[t*4+3];
    SS[t] = s0; __syncthreads();
    for (int off = 1; off < 256; off <<= 1) {
        int y = (t >= off) ? SS[t - off] : 0;
        __syncthreads();
        SS[t] += y;
        __syncthreads();
    }
    int e0 = (t ? SS[t - 1] : 0) + boff[blockIdx.x];
    int4 ov;
    int a;
    a = L[t*4+0]; ov.x = e0; e0 += a;
    a = L[t*4+1]; ov.y = e0; e0 += a;
    a = L[t*4+2]; ov.z = e0; e0 += a;
    a = L[t*4+3]; ov.w = e0; e0 += a;
    int idx0 = base + t * 4;
    if (idx0 + 3 < n) {
        *(int4*)(segptr + idx0) = ov;
        *(int4*)(cursor + idx0) = ov;
    } else {
        int vals[4] = {ov.x, ov.y, ov.z, ov.w};
        for (int k = 0; k < 4; ++k)
            if (idx0 + k < n) { segptr[idx0 + k] = vals[k]; cursor[idx0 + k] = vals[k]; }
    }
}

// ---------------- K3: scatter edges into composite CSR ----------------
__global__ void scatter_kernel(const int* __restrict__ ei, const int* __restrict__ et,
                               int* __restrict__ cursor, unsigned* __restrict__ esrc,
                               int N, int E) {
    int e = blockIdx.x * blockDim.x + threadIdx.x;
    if (e >= E) return;
    int src = ei[e];
    int dst = ei[E + e];
    int r   = et[e];
    int pos = atomicAdd(&cursor[dst * RNUM + r], 1);
    esrc[pos] = (unsigned)src;
}

// ---------------- prep2: count + xhalf + wconv_rgcn + wconv_qkvs fused ----------------
__global__ __launch_bounds__(256)
void prep2_kernel(const int* __restrict__ ei, const int* __restrict__ et,
                  int* __restrict__ segcnt, int E, int eb,
                  const float* __restrict__ x, us* __restrict__ xh,
                  const float* __restrict__ Wrel, const float* __restrict__ Wroot,
                  ushort4* __restrict__ Btr,
                  const float* __restrict__ Wq, const float* __restrict__ Wk,
                  const float* __restrict__ Wv, const float* __restrict__ Ws,
                  ushort4* __restrict__ Btq, int xblocks) {
    int b = blockIdx.x;
    if (b < eb) {
        int e = b * 256 + threadIdx.x;
        if (e < E) {
            int dst = ei[E + e];
            int r   = et[e];
            atomicAdd(&segcnt[dst * RNUM + r], 1);
        }
    } else if (b < eb + xblocks) {
        int i = (b - eb) * 256 + threadIdx.x;      // i < N*G/8 exactly
        float4 a = ((const float4*)x)[2*i];
        float4 c = ((const float4*)x)[2*i+1];
        ushort4 u0 = { f2h(a.x), f2h(a.y), f2h(a.z), f2h(a.w) };
        ushort4 u1 = { f2h(c.x), f2h(c.y), f2h(c.z), f2h(c.w) };
        ((ushort4*)xh)[2*i]   = u0;
        ((ushort4*)xh)[2*i+1] = u1;
    } else if (b < eb + xblocks + 112) {
        int idx = (b - eb - xblocks) * 256 + threadIdx.x;   // < 224*128 exactly
        int kq = idx >> 7, n = idx & 127;
        ushort4 o;
        us* op = (us*)&o;
#pragma unroll
        for (int i = 0; i < 4; ++i) {
            int k = 4 * kq + i;
            float v = (k < 768) ? Wrel[(size_t)k * 128 + n] : Wroot[(size_t)(k - 768) * 128 + n];
            op[i] = f2h(v);
        }
        Btr[idx] = o;
    } else {
        int idx = (b - eb - xblocks - 112) * 256 + threadIdx.x;  // < 32*512 exactly
        int kq = idx >> 9, n = idx & 511;
        int quad = n >> 7, nl = n & 127;
        const float* W = (quad == 0) ? Wq : (quad == 1) ? Wk : (quad == 2) ? Wv : Ws;
        ushort4 o;
        us* op = (us*)&o;
#pragma unroll
        for (int i = 0; i < 4; ++i) {
            int k = 4 * kq + i;
            op[i] = f2h(W[(size_t)k * 128 + nl]);
        }
        Btq[idx] = o;
    }
}

// ---------------- K4: aggregation (wave/node, 8-deep gathers, scalar rel-flush) ----------------
__global__ __launch_bounds__(256)
void agg_kernel(const us* __restrict__ xh, const int* __restrict__ segptr,
                const unsigned* __restrict__ esrc, us* __restrict__ meanh, int N) {
    const int wv = threadIdx.x >> 6, l = threadIdx.x & 63;
    const int i = blockIdx.x * 4 + wv;
    if (i >= N) return;
    const int e0 = __builtin_amdgcn_readfirstlane(segptr[i * RNUM]);
    const int e1 = __builtin_amdgcn_readfirstlane(segptr[i * RNUM + RNUM]);

    int rcur = 0;
    int sstart = e0;
    int bnext = __builtin_amdgcn_readfirstlane(segptr[i * RNUM + 1]);
    float2 a = {0.f, 0.f};
    us* wbase = meanh + (size_t)i * 768 + 2 * l;

#define FLUSH() { \
    float sc_ = 1.f / fmaxf((float)(bnext - sstart), 1.f); \
    ushort2 t2_ = { f2h(a.x * sc_), f2h(a.y * sc_) }; \
    *(ushort2*)(wbase + rcur * 128) = t2_; \
    a.x = 0.f; a.y = 0.f; \
    sstart = bnext; ++rcur; \
    if (rcur < RNUM) bnext = __builtin_amdgcn_readfirstlane(segptr[i * RNUM + rcur + 1]); }

#define GET(J) ((unsigned)__shfl((int)pv, (J)))
#define LX(Q)  (*(const ushort2*)(xh + (size_t)(Q) * G + 2 * l))
#define STEP(U) { while (p >= bnext && rcur < RNUM - 1) FLUSH(); \
                  a.x += h2f((U).x); a.y += h2f((U).y); ++p; }

    int p = e0;
    for (int wb = e0; wb < e1; wb += 64) {
        const int nc = min(64, e1 - wb);
        unsigned pv = (wb + l < e1) ? esrc[wb + l] : 0u;
        int j = 0;
        while (j + 8 <= nc) {
            unsigned q0 = GET(j+0), q1 = GET(j+1), q2 = GET(j+2), q3 = GET(j+3);
            unsigned q4 = GET(j+4), q5 = GET(j+5), q6 = GET(j+6), q7 = GET(j+7);
            ushort2 u0 = LX(q0), u1 = LX(q1), u2 = LX(q2), u3 = LX(q3);
            ushort2 u4 = LX(q4), u5 = LX(q5), u6 = LX(q6), u7 = LX(q7);
            STEP(u0); STEP(u1); STEP(u2); STEP(u3);
            STEP(u4); STEP(u5); STEP(u6); STEP(u7);
            j += 8;
        }
        while (j + 2 <= nc) {
            unsigned q0 = GET(j), q1 = GET(j+1);
            ushort2 u0 = LX(q0), u1 = LX(q1);
            STEP(u0); STEP(u1);
            j += 2;
        }
        if (j < nc) {
            unsigned q0 = GET(j);
            ushort2 u0 = LX(q0);
            STEP(u0);
            ++j;
        }
    }
    while (rcur < RNUM) FLUSH();
#undef STEP
#undef LX
#undef GET
#undef FLUSH
}

// ---------------- K5: FUSED rgcn GEMM + qkvs GEMM (LDS handoff, no xrh) ----------------
__global__ __launch_bounds__(256)
void rgcn_qkvs(const us* __restrict__ xh, const us* __restrict__ meanh,
               const ushort4* __restrict__ Btr, const float* __restrict__ brg,
               const ushort4* __restrict__ Btq,
               const float* __restrict__ bq, const float* __restrict__ bk,
               const float* __restrict__ bv, const float* __restrict__ bs,
               us* __restrict__ qsh, us* __restrict__ kvh, int N) {
    __shared__ us X[128][136];
    const int tid = threadIdx.x;
    const int w = tid >> 6, l = tid & 63;
    const int lh = l >> 4, lm = l & 15;
    const int blockbase = blockIdx.x * 128;
    const int rowbase = blockbase + w * 32;

    // ---------- phase 1: RGCN ----------
    {
        const us* am[2];
        const us* ar[2];
#pragma unroll
        for (int tt = 0; tt < 2; ++tt) {
            int gr = min(rowbase + tt * 16 + lm, N - 1);
            am[tt] = meanh + (size_t)gr * 768;
            ar[tt] = xh + (size_t)gr * 128;
        }

        f32x4 acc[2][8];
#pragma unroll
        for (int tt = 0; tt < 2; ++tt)
#pragma unroll
            for (int ct = 0; ct < 8; ++ct) {
                float b = brg[ct * 16 + lm];
                acc[tt][ct] = (f32x4){b, b, b, b};
            }

        for (int s = 0; s < 24; ++s) {
            const int kqg = s * 8 + lh;
            const ushort4* B0 = Btr + (size_t)kqg * 128 + lm;
            const ushort4* B1 = B0 + 4 * 128;
            FragU bf[8];
#pragma unroll
            for (int ct = 0; ct < 8; ++ct) { bf[ct].u[0] = B0[ct * 16]; bf[ct].u[1] = B1[ct * 16]; }
#pragma unroll
            for (int tt = 0; tt < 2; ++tt) {
                FragU af;
                af.u[0] = *(const ushort4*)(am[tt] + s * 32 + 4 * lh);
                af.u[1] = *(const ushort4*)(am[tt] + s * 32 + 4 * lh + 16);
#pragma unroll
                for (int ct = 0; ct < 8; ++ct)
                    acc[tt][ct] = __builtin_amdgcn_mfma_f32_16x16x32_f16(af.v, bf[ct].v, acc[tt][ct], 0, 0, 0);
            }
        }
#pragma unroll
        for (int s = 0; s < 4; ++s) {
            const int kqg = 192 + s * 8 + lh;
            const ushort4* B0 = Btr + (size_t)kqg * 128 + lm;
            const ushort4* B1 = B0 + 4 * 128;
            FragU bf[8];
#pragma unroll
            for (int ct = 0; ct < 8; ++ct) { bf[ct].u[0] = B0[ct * 16]; bf[ct].u[1] = B1[ct * 16]; }
#pragma unroll
            for (int tt = 0; tt < 2; ++tt) {
                FragU af;
                af.u[0] = *(const ushort4*)(ar[tt] + s * 32 + 4 * lh);
                af.u[1] = *(const ushort4*)(ar[tt] + s * 32 + 4 * lh + 16);
#pragma unroll
                for (int ct = 0; ct < 8; ++ct)
                    acc[tt][ct] = __builtin_amdgcn_mfma_f32_16x16x32_f16(af.v, bf[ct].v, acc[tt][ct], 0, 0, 0);
            }
        }

        // D-frag -> LDS (same f16 rounding as old xrh roundtrip)
#pragma unroll
        for (int tt = 0; tt < 2; ++tt)
#pragma unroll
            for (int ct = 0; ct < 8; ++ct)
#pragma unroll
                for (int i = 0; i < 4; ++i)
                    X[w * 32 + tt * 16 + 4 * lh + i][ct * 16 + lm] = f2h(acc[tt][ct][i]);
    }
    __syncthreads();

    // ---------- phase 2: q|k|v|skip ; wave w = quadrant w ----------
    const int quad = w;
    const float* bias = (quad == 0) ? bq : (quad == 1) ? bk : (quad == 2) ? bv : bs;

    for (int tp = 0; tp < 4; ++tp) {
        f32x4 a2[2][8];
#pragma unroll
        for (int tt = 0; tt < 2; ++tt)
#pragma unroll
            for (int ct = 0; ct < 8; ++ct) {
                float b = bias[ct * 16 + lm];
                a2[tt][ct] = (f32x4){b, b, b, b};
            }
#pragma unroll
        for (int s = 0; s < 4; ++s) {
            const int kq = s * 8 + lh;
            const ushort4* B0 = Btq + (size_t)kq * 512 + quad * 128 + lm;
            const ushort4* B1 = B0 + 4 * 512;
            FragU bf[8];
#pragma unroll
            for (int ct = 0; ct < 8; ++ct) { bf[ct].u[0] = B0[ct * 16]; bf[ct].u[1] = B1[ct * 16]; }
#pragma unroll
            for (int tt = 0; tt < 2; ++tt) {
                const int row = tp * 32 + tt * 16 + lm;
                FragU af;
                af.u[0] = *(const ushort4*)(&X[row][4 * kq]);
                af.u[1] = *(const ushort4*)(&X[row][4 * kq + 16]);
#pragma unroll
                for (int ct = 0; ct < 8; ++ct)
                    a2[tt][ct] = __builtin_amdgcn_mfma_f32_16x16x32_f16(af.v, bf[ct].v, a2[tt][ct], 0, 0, 0);
            }
        }
        if (quad == 0 || quad == 3) {
            const int off = (quad == 0) ? 0 : 128;
#pragma unroll
            for (int tt = 0; tt < 2; ++tt)
#pragma unroll
                for (int ct = 0; ct < 8; ++ct)
#pragma unroll
                    for (int i = 0; i < 4; ++i) {
                        int r = blockbase + tp * 32 + tt * 16 + 4 * lh + i;
                        if (r < N) qsh[(size_t)r * 256 + off + ct * 16 + lm] = f2h(a2[tt][ct][i]);
                    }
        } else {
            const int off = (quad == 1) ? 0 : 2;
#pragma unroll
            for (int tt = 0; tt < 2; ++tt)
#pragma unroll
                for (int ct = 0; ct < 8; ++ct)
#pragma unroll
                    for (int i = 0; i < 4; ++i) {
                        int r = blockbase + tp * 32 + tt * 16 + 4 * lh + i;
                        int col = ct * 16 + lm;
                        if (r < N) kvh[(size_t)r * 256 + (col >> 1) * 4 + (col & 1) + off] = f2h(a2[tt][ct][i]);
                    }
        }
    }
}

// ---------------- K7: attention — 32 lanes/node, 2 nodes/wave, 8-deep online softmax + BN ----------------
__global__ __launch_bounds__(256)
void attn_kernel(const us* __restrict__ qsh, const us* __restrict__ kvh,
                 const int* __restrict__ segptr, const unsigned* __restrict__ esrc,
                 float* __restrict__ out, float* __restrict__ bnS,
                 float* __restrict__ bnQ, int N) {
    __shared__ float sS[128], sQ[128];
    const int tid = threadIdx.x;
    if (tid < 128) { sS[tid] = 0.f; sQ[tid] = 0.f; }
    __syncthreads();

    const int wv = tid >> 6, l = tid & 63;
    const int hh = l >> 5, ll = l & 31;
    const int stride = gridDim.x * 8;
    const float QS = 0.17677669529663687f;   // 1/sqrt(32)
    float4 bsum = {0,0,0,0}, bsq = {0,0,0,0};

#define SCORE(D, S) { \
    float2 ka_ = h22((D).x), kb_ = h22((D).z); \
    float t_ = q4.x*ka_.x + q4.y*ka_.y + q4.z*kb_.x + q4.w*kb_.y; \
    t_ += __shfl_xor(t_, 1, 8); t_ += __shfl_xor(t_, 2, 8); t_ += __shfl_xor(t_, 4, 8); \
    S = t_; }

    for (int ibase = blockIdx.x * 8 + wv * 2; ibase < N; ibase += stride) {
        const bool act = (ibase + hh) < N;
        const int i = min(ibase + hh, N - 1);

        int2 qu = *(const int2*)(qsh + (size_t)i * 256 + 4 * ll);
        float2 qa = h22(qu.x), qb = h22(qu.y);
        float4 q4 = { qa.x * QS, qa.y * QS, qb.x * QS, qb.y * QS };

        float m = -INFINITY, den = 0.f;
        float4 acc = {0,0,0,0};
        const int e0 = segptr[(size_t)i * RNUM], e1 = segptr[(size_t)i * RNUM + RNUM];

        for (int wb = e0; wb < e1; wb += 32) {
            const int nc = min(32, e1 - wb);
            unsigned pv = (wb + ll < e1) ? esrc[wb + ll] : 0u;
            int j = 0;
            for (; j + 8 <= nc; j += 8) {
                unsigned p0 = (unsigned)__shfl((int)pv, j+0, 32);
                unsigned p1 = (unsigned)__shfl((int)pv, j+1, 32);
                unsigned p2 = (unsigned)__shfl((int)pv, j+2, 32);
                unsigned p3 = (unsigned)__shfl((int)pv, j+3, 32);
                unsigned p4 = (unsigned)__shfl((int)pv, j+4, 32);
                unsigned p5 = (unsigned)__shfl((int)pv, j+5, 32);
                unsigned p6 = (unsigned)__shfl((int)pv, j+6, 32);
                unsigned p7 = (unsigned)__shfl((int)pv, j+7, 32);
                int4 d0 = *(const int4*)(kvh + (size_t)p0 * 256 + 8 * ll);
                int4 d1 = *(const int4*)(kvh + (size_t)p1 * 256 + 8 * ll);
                int4 d2 = *(const int4*)(kvh + (size_t)p2 * 256 + 8 * ll);
                int4 d3 = *(const int4*)(kvh + (size_t)p3 * 256 + 8 * ll);
                int4 d4 = *(const int4*)(kvh + (size_t)p4 * 256 + 8 * ll);
                int4 d5 = *(const int4*)(kvh + (size_t)p5 * 256 + 8 * ll);
                int4 d6 = *(const int4*)(kvh + (size_t)p6 * 256 + 8 * ll);
                int4 d7 = *(const int4*)(kvh + (size_t)p7 * 256 + 8 * ll);
                float s0, s1, s2, s3, s4, s5, s6, s7;
                SCORE(d0, s0); SCORE(d1, s1); SCORE(d2, s2); SCORE(d3, s3);
                SCORE(d4, s4); SCORE(d5, s5); SCORE(d6, s6); SCORE(d7, s7);
                float mx = fmaxf(m, fmaxf(
                    fmaxf(fmaxf(s0, s1), fmaxf(s2, s3)),
                    fmaxf(fmaxf(s4, s5), fmaxf(s6, s7))));
                float rs = __expf(m - mx);
                float w0 = __expf(s0 - mx), w1 = __expf(s1 - mx);
                float w2 = __expf(s2 - mx), w3 = __expf(s3 - mx);
                float w4 = __expf(s4 - mx), w5 = __expf(s5 - mx);
                float w6 = __expf(s6 - mx), w7 = __expf(s7 - mx);
                den = den * rs + (((w0 + w1) + (w2 + w3)) + ((w4 + w5) + (w6 + w7)));
                float2 va0 = h22(d0.y), vb0 = h22(d0.w);
                float2 va1 = h22(d1.y), vb1 = h22(d1.w);
                float2 va2 = h22(d2.y), vb2 = h22(d2.w);
                float2 va3 = h22(d3.y), vb3 = h22(d3.w);
                float2 va4 = h22(d4.y), vb4 = h22(d4.w);
                float2 va5 = h22(d5.y), vb5 = h22(d5.w);
                float2 va6 = h22(d6.y), vb6 = h22(d6.w);
                float2 va7 = h22(d7.y), vb7 = h22(d7.w);
                acc.x = acc.x * rs + ((w0*va0.x + w1*va1.x) + (w2*va2.x + w3*va3.x))
                                   + ((w4*va4.x + w5*va5.x) + (w6*va6.x + w7*va7.x));
                acc.y = acc.y * rs + ((w0*va0.y + w1*va1.y) + (w2*va2.y + w3*va3.y))
                                   + ((w4*va4.y + w5*va5.y) + (w6*va6.y + w7*va7.y));
                acc.z = acc.z * rs + ((w0*vb0.x + w1*vb1.x) + (w2*vb2.x + w3*vb3.x))
                                   + ((w4*vb4.x + w5*vb5.x) + (w6*vb6.x + w7*vb7.x));
                acc.w = acc.w * rs + ((w0*vb0.y + w1*vb1.y) + (w2*vb2.y + w3*vb3.y))
                                   + ((w4*vb4.y + w5*vb5.y) + (w6*vb6.y + w7*vb7.y));
                m = mx;
            }
            for (; j + 4 <= nc; j += 4) {
                unsigned p0 = (unsigned)__shfl((int)pv, j+0, 32);
                unsigned p1 = (unsigned)__shfl((int)pv, j+1, 32);
                unsigned p2 = (unsigned)__shfl((int)pv, j+2, 32);
                unsigned p3 = (unsigned)__shfl((int)pv, j+3, 32);
                int4 d0 = *(const int4*)(kvh + (size_t)p0 * 256 + 8 * ll);
                int4 d1 = *(const int4*)(kvh + (size_t)p1 * 256 + 8 * ll);
                int4 d2 = *(const int4*)(kvh + (size_t)p2 * 256 + 8 * ll);
                int4 d3 = *(const int4*)(kvh + (size_t)p3 * 256 + 8 * ll);
                float s0, s1, s2, s3;
                SCORE(d0, s0); SCORE(d1, s1); SCORE(d2, s2); SCORE(d3, s3);
                float mx = fmaxf(m, fmaxf(fmaxf(s0, s1), fmaxf(s2, s3)));
                float rs = __expf(m - mx);
                float w0 = __expf(s0 - mx), w1 = __expf(s1 - mx);
                float w2 = __expf(s2 - mx), w3 = __expf(s3 - mx);
                den = den * rs + ((w0 + w1) + (w2 + w3));
                float2 va0 = h22(d0.y), vb0 = h22(d0.w);
                float2 va1 = h22(d1.y), vb1 = h22(d1.w);
                float2 va2 = h22(d2.y), vb2 = h22(d2.w);
                float2 va3 = h22(d3.y), vb3 = h22(d3.w);
                acc.x = acc.x * rs + w0*va0.x + w1*va1.x + w2*va2.x + w3*va3.x;
                acc.y = acc.y * rs + w0*va0.y + w1*va1.y + w2*va2.y + w3*va3.y;
                acc.z = acc.z * rs + w0*vb0.x + w1*vb1.x + w2*vb2.x + w3*vb3.x;
                acc.w = acc.w * rs + w0*vb0.y + w1*vb1.y + w2*vb2.y + w3*vb3.y;
                m = mx;
            }
            for (; j < nc; ++j) {
                unsigned p0 = (unsigned)__shfl((int)pv, j, 32);
                int4 d0 = *(const int4*)(kvh + (size_t)p0 * 256 + 8 * ll);
                float s0; SCORE(d0, s0);
                float mx = fmaxf(m, s0);
                float rs = __expf(m - mx);
                float w0 = __expf(s0 - mx);
                den = den * rs + w0;
                float2 va0 = h22(d0.y), vb0 = h22(d0.w);
                acc.x = acc.x * rs + w0 * va0.x;
                acc.y = acc.y * rs + w0 * va0.y;
                acc.z = acc.z * rs + w0 * vb0.x;
                acc.w = acc.w * rs + w0 * vb0.y;
                m = mx;
            }
        }

        float inv = 1.f / (den + 1e-16f);
        int2 su = *(const int2*)(qsh + (size_t)i * 256 + 128 + 4 * ll);
        float2 sa = h22(su.x), sb = h22(su.y);
        float4 o = { acc.x * inv + sa.x, acc.y * inv + sa.y,
                     acc.z * inv + sb.x, acc.w * inv + sb.y };
        if (act) {
            *(float4*)(out + (size_t)i * OUTW + 4 * ll) = o;
            bsum.x += o.x; bsum.y += o.y; bsum.z += o.z; bsum.w += o.w;
            bsq.x += o.x*o.x; bsq.y += o.y*o.y; bsq.z += o.z*o.z; bsq.w += o.w*o.w;
        }
    }
#undef SCORE

    atomicAdd(&sS[4*ll + 0], bsum.x);
    atomicAdd(&sS[4*ll + 1], bsum.y);
    atomicAdd(&sS[4*ll + 2], bsum.z);
    atomicAdd(&sS[4*ll + 3], bsum.w);
    atomicAdd(&sQ[4*ll + 0], bsq.x);
    atomicAdd(&sQ[4*ll + 1], bsq.y);
    atomicAdd(&sQ[4*ll + 2], bsq.z);
    atomicAdd(&sQ[4*ll + 3], bsq.w);
    __syncthreads();
    if (tid < 128) {
        atomicAdd(&bnS[tid], sS[tid]);
        atomicAdd(&bnQ[tid], sQ[tid]);
    }
}

// ---------------- K8: BN stats (inline) + apply + LeakyReLU ----------------
__global__ __launch_bounds__(256)
void apply_kernel(float* __restrict__ out, const float* __restrict__ bnS,
                  const float* __restrict__ bnQ, const float* __restrict__ gamma,
                  const float* __restrict__ beta, int N, int total4) {
    __shared__ float A_s[128], B_s[128];
    const int tid = threadIdx.x;
    if (tid < 128) {
        float fN  = (float)N;
        float mu  = bnS[tid] / fN;
        float var = bnQ[tid] / fN - mu * mu;
        float rv  = rsqrtf(var + 1e-5f);
        float A   = rv * gamma[tid];
        A_s[tid] = A;
        B_s[tid] = beta[tid] - mu * A;
    }
    __syncthreads();
    for (int idx4 = blockIdx.x * 256 + tid; idx4 < total4; idx4 += gridDim.x * 256) {
        float4 v = ((const float4*)out)[idx4];
        int c0 = (idx4 * 4) & 127;
        float y;
        y = A_s[c0    ] * v.x + B_s[c0    ]; v.x = (y > 0.f) ? y : 0.01f * y;
        y = A_s[c0 + 1] * v.y + B_s[c0 + 1]; v.y = (y > 0.f) ? y : 0.01f * y;
        y = A_s[c0 + 2] * v.z + B_s[c0 + 2]; v.z = (y > 0.f) ? y : 0.01f * y;
        y = A_s[c0 + 3] * v.w + B_s[c0 + 3]; v.w = (y > 0.f) ? y : 0.01f * y;
        ((float4*)out)[idx4] = v;
    }
}

// ---------------- launch ----------------
static inline char* alignp(char* p) {
    return (char*)(((uintptr_t)p + 255) & ~(uintptr_t)255);
}

extern "C" void kernel_launch(void* const* d_in, const int* in_sizes, int n_in,
                              void* d_out, int out_size, void* d_ws, size_t ws_size,
                              hipStream_t stream) {
    const float* x     = (const float*)d_in[0];
    const int*   ei    = (const int*)  d_in[2];
    const int*   et    = (const int*)  d_in[3];
    const float* Wrel  = (const float*)d_in[4];
    const float* Wroot = (const float*)d_in[5];
    const float* brg   = (const float*)d_in[6];
    const float* Wq    = (const float*)d_in[7];
    const float* bq    = (const float*)d_in[8];
    const float* Wk    = (const float*)d_in[9];
    const float* bk    = (const float*)d_in[10];
    const float* Wv    = (const float*)d_in[11];
    const float* bv    = (const float*)d_in[12];
    const float* Wsk   = (const float*)d_in[13];
    const float* bsk   = (const float*)d_in[14];
    const float* gamma = (const float*)d_in[15];
    const float* beta  = (const float*)d_in[16];
    float* out = (float*)d_out;

    const int N = in_sizes[0] / G;
    const int E = in_sizes[3];
    const int NSEG = N * RNUM;
    const int NB_SCAN = (NSEG + 1023) / 1024;   // <= 512

    // ---- workspace carve ----
    char* w = (char*)d_ws;
    int* segcnt = (int*)w;           w += (size_t)NSEG * 4;
    float* bnS = (float*)w;          w += 128 * 4;
    float* bnQ = (float*)w;          w += 128 * 4;
    size_t zero_bytes = (size_t)(w - (char*)d_ws);
    w = alignp(w);
    int* bsum  = (int*)w;            w += 512 * 4;
    int* boff  = (int*)w;            w += 513 * 4;
    w = alignp(w);
    int* segptr = (int*)w;           w += (size_t)(NSEG + 1) * 4;
    w = alignp(w);
    int* cursor = (int*)w;           w += (size_t)NSEG * 4;
    w = alignp(w);
    unsigned* esrc = (unsigned*)w;   w += (size_t)E * 4;
    w = alignp(w);
    us* xh     = (us*)w;             w += (size_t)N * G * 2;
    w = alignp(w);
    ushort4* Btr = (ushort4*)w;      w += (size_t)224 * 128 * 8;
    w = alignp(w);
    ushort4* Btq = (ushort4*)w;      w += (size_t)32 * 512 * 8;
    w = alignp(w);
    // aliased region: meanh [N][768] fp16 row-major (76.8MB);
    // later qsh [N][256] fp16 (25.6MB) + kvh [N][256] fp16 (25.6MB)
    us* meanh = (us*)w;
    us* qsh   = (us*)w;
    us* kvh   = (us*)(w + (size_t)N * 256 * 2);

    hipMemsetAsync(d_ws, 0, zero_bytes, stream);

    int eb = (E + 255) / 256;
    int xblocks = N * G / 8 / 256;               // 3125
    prep2_kernel<<<eb + xblocks + 112 + 64, 256, 0, stream>>>(
        ei, et, segcnt, E, eb, x, xh, Wrel, Wroot, Btr, Wq, Wk, Wv, Wsk, Btq, xblocks);

    scan_part<<<NB_SCAN, 256, 0, stream>>>(segcnt, bsum, NSEG);
    scan_top<<<1, 512, 0, stream>>>(bsum, boff, segptr, NB_SCAN, NSEG);
    scan_apply<<<NB_SCAN, 256, 0, stream>>>(segcnt, boff, segptr, cursor, NSEG);

    scatter_kernel<<<eb, 256, 0, stream>>>(ei, et, cursor, esrc, N, E);

    agg_kernel<<<(N + 3) / 4, 256, 0, stream>>>(xh, segptr, esrc, meanh, N);

    rgcn_qkvs<<<(N + 127) / 128, 256, 0, stream>>>(xh, meanh, Btr, brg, Btq,
                                                   bq, bk, bv, bsk, qsh, kvh, N);

    attn_kernel<<<2048, 256, 0, stream>>>(qsh, kvh, segptr, esrc, out, bnS, bnQ, N);

    int total4 = N * OUTW / 4;
    apply_kernel<<<2048, 256, 0, stream>>>(out, bnS, bnQ, gamma, beta, N, total4);
}